// Round 18
// baseline (103.700 us; speedup 1.0000x reference)
//
#include <hip/hip_runtime.h>
#include <hip/hip_bf16.h>
#include <math.h>

#define B_   2
#define T_   2048
#define C_   768
#define NH   12
#define HS   64
#define NSEG 64
#define SEGLEN 32
#define CX   1536   // uxv row stride (u | xv)

typedef __attribute__((ext_vector_type(8))) short short8;
typedef __attribute__((ext_vector_type(4))) short short4v;
typedef __attribute__((ext_vector_type(4))) float f32x4;
typedef __attribute__((ext_vector_type(16))) float f32x16;
typedef __attribute__((ext_vector_type(2))) unsigned int uint2v;
typedef __attribute__((ext_vector_type(4))) unsigned int uint4v;

static __device__ inline unsigned short f2b(float f) {
  __hip_bfloat16 h = __float2bfloat16(f);
  unsigned short u;
  __builtin_memcpy(&u, &h, 2);
  return u;
}
static __device__ inline float b2f(unsigned short u) {
  unsigned int x = ((unsigned int)u) << 16;
  float f;
  __builtin_memcpy(&f, &x, 4);
  return f;
}
static __device__ inline unsigned cvtpk(float a, float b) {
  unsigned r;
  asm("v_cvt_pk_bf16_f32 %0, %1, %2" : "=v"(r) : "v"(a), "v"(b));
  return r;
}

#define GLOAD_LDS16(gp, lp)                                                        \
  __builtin_amdgcn_global_load_lds((const __attribute__((address_space(1))) void*)(gp), \
                                   (__attribute__((address_space(3))) void*)(lp), 16, 0, 0)

// ---------------- fused f32 -> bf16 casts (x, W_la|W_v -> Wcat, W_proj) -------------
__global__ __launch_bounds__(256) void cast_all(const float* __restrict__ x,
                                                const float* __restrict__ wla,
                                                const float* __restrict__ wv,
                                                const float* __restrict__ wp,
                                                __hip_bfloat16* __restrict__ xb,
                                                __hip_bfloat16* __restrict__ wcat,
                                                __hip_bfloat16* __restrict__ wpb) {
  const int NX4 = (B_ * T_ * C_) / 4;     // 786432
  const int NW4 = (C_ * C_) / 4;          // 147456
  const int TOT = NX4 + 3 * NW4;
  int i = blockIdx.x * 256 + threadIdx.x;
  int st = gridDim.x * 256;
  for (; i < TOT; i += st) {
    const float* s;
    unsigned short* d;
    if (i < NX4) { s = x + (size_t)i * 4; d = (unsigned short*)xb + (size_t)i * 4; }
    else if (i < NX4 + NW4) { int j = i - NX4; s = wla + (size_t)j * 4; d = (unsigned short*)wcat + (size_t)j * 4; }
    else if (i < NX4 + 2 * NW4) { int j = i - NX4 - NW4; s = wv + (size_t)j * 4; d = (unsigned short*)wcat + (size_t)(C_ * C_) + (size_t)j * 4; }
    else { int j = i - NX4 - 2 * NW4; s = wp + (size_t)j * 4; d = (unsigned short*)wpb + (size_t)j * 4; }
    float4 v = *(const float4*)s;
    short4v o;
    o.x = (short)f2b(v.x); o.y = (short)f2b(v.y); o.z = (short)f2b(v.z); o.w = (short)f2b(v.w);
    *(short4v*)d = o;
  }
}

// ---------------- bf16 MFMA GEMM: C[m,n] = sum_k A[m,k] * Bw[n,k] -------------------
template <int BM, bool OB16>
__global__ __launch_bounds__(256) void gemm_bf16(const __hip_bfloat16* __restrict__ A,
                                                 const __hip_bfloat16* __restrict__ Bw,
                                                 void* __restrict__ Cv,
                                                 int M, int N, int K) {
  __shared__ __hip_bfloat16 As[BM * 64];
  __shared__ __hip_bfloat16 Bs[128 * 64];
  const int tid = threadIdx.x;
  const int w = tid >> 6, lane = tid & 63;
  const int bm = blockIdx.x * BM, bn = blockIdx.y * 128;
  const int q16 = lane & 15, lg = lane >> 4;

  constexpr int NACC = (BM == 128) ? 4 : 2;
  f32x4 acc[4][NACC];
#pragma unroll
  for (int i = 0; i < 4; ++i)
#pragma unroll
    for (int j = 0; j < NACC; ++j) acc[i][j] = (f32x4){0.f, 0.f, 0.f, 0.f};

  const int srow = (lane >> 3);
  const int soff0 = (lane & 7) * 16;
  const int sw = (lane & 7) << 4;
  constexpr int ACH = BM / 8;
  constexpr int CPW = (ACH + 16) / 4;

  for (int k0 = 0; k0 < K; k0 += 64) {
    __syncthreads();
#pragma unroll
    for (int c = 0; c < CPW; ++c) {
      int gc = w * CPW + c;
      int isB = gc >= ACH;
      int ci = isB ? gc - ACH : gc;
      int row = ci * 8 + srow;
      int soff = soff0 ^ ((row & 7) << 4);
      const __hip_bfloat16* gp =
          (isB ? Bw + (size_t)(bn + row) * K : A + (size_t)(bm + row) * K) + k0 + (soff >> 1);
      __hip_bfloat16* lp = (isB ? Bs : As) + ci * 512;
      GLOAD_LDS16(gp, lp);
    }
    __syncthreads();
#pragma unroll
    for (int ks = 0; ks < 2; ++ks) {
      short8 af[4], bf[NACC];
      const int colb = ks * 64 + lg * 16;
#pragma unroll
      for (int i = 0; i < 4; ++i) {
        int ra = (BM == 128) ? ((w >> 1) * 64 + i * 16 + q16) : (i * 16 + q16);
        af[i] = *(const short8*)((const char*)As + ra * 128 + (colb ^ sw));
      }
#pragma unroll
      for (int j = 0; j < NACC; ++j) {
        int rb = (BM == 128) ? ((w & 1) * 64 + j * 16 + q16) : (w * 32 + j * 16 + q16);
        bf[j] = *(const short8*)((const char*)Bs + rb * 128 + (colb ^ sw));
      }
#pragma unroll
      for (int i = 0; i < 4; ++i)
#pragma unroll
        for (int j = 0; j < NACC; ++j)
          acc[i][j] = __builtin_amdgcn_mfma_f32_16x16x32_bf16(af[i], bf[j], acc[i][j], 0, 0, 0);
    }
  }
#pragma unroll
  for (int i = 0; i < 4; ++i) {
#pragma unroll
    for (int r = 0; r < 4; ++r) {
      int m = (BM == 128) ? (bm + (w >> 1) * 64 + i * 16 + lg * 4 + r)
                          : (bm + i * 16 + lg * 4 + r);
      int nb = (BM == 128) ? (bn + (w & 1) * 64 + q16) : (bn + w * 32 + q16);
      if (OB16) {
        unsigned short* cp = (unsigned short*)Cv + (size_t)m * N + nb;
#pragma unroll
        for (int j = 0; j < NACC; ++j) cp[j * 16] = f2b(acc[i][j][r]);
      } else {
        float* cp = (float*)Cv + (size_t)m * N + nb;
#pragma unroll
        for (int j = 0; j < NACC; ++j) cp[j * 16] = acc[i][j][r];
      }
    }
  }
}

// ---------------- Scan pass A: segment end-carries (bf16 u, prefetched loads) -------
__global__ __launch_bounds__(256) void scan_seg(const unsigned short* __restrict__ uxv,
                                                const float* __restrict__ la_coef,
                                                float* __restrict__ segend) {
  int cid = blockIdx.x * 4 + (threadIdx.x >> 6);  // bh*NSEG + seg
  int d   = threadIdx.x & 63;
  int seg = cid & (NSEG - 1);
  int bh  = cid >> 6;
  int h   = bh % NH;
  int b   = bh / NH;
  float c  = la_coef[h];
  float oc = 1.f - c;
  int t0 = seg * SEGLEN;
  const unsigned short* up = uxv + ((size_t)b * T_ + t0) * CX + h * HS + d;
  float uv[SEGLEN];
#pragma unroll
  for (int i = 0; i < SEGLEN; ++i) uv[i] = b2f(up[(size_t)i * CX]);
  float y = 0.f;
#pragma unroll
  for (int i = 0; i < SEGLEN; ++i) y = fmaf(c, y, oc * uv[i]);
  segend[(size_t)cid * HS + d] = y;
}

// ---------------- Scan pass B: combine segment carries (prefetched) -----------------
__global__ __launch_bounds__(256) void scan_b(const float* __restrict__ la_coef,
                                              const float* __restrict__ segend,
                                              float* __restrict__ carryin) {
  int s = blockIdx.x * 256 + threadIdx.x;  // (b,h,d)
  if (s >= B_ * NH * HS) return;
  int d  = s & 63;
  int bh = s >> 6;
  int h  = bh % NH;
  float c = la_coef[h];
  float cl = c;
#pragma unroll
  for (int i = 0; i < 5; ++i) cl *= cl;  // c^32
  float sv[NSEG];
#pragma unroll
  for (int seg = 0; seg < NSEG; ++seg)
    sv[seg] = segend[(size_t)(bh * NSEG + seg) * HS + d];
  float h0 = 0.f;
#pragma unroll
  for (int seg = 0; seg < NSEG; ++seg) {
    carryin[(size_t)(bh * NSEG + seg) * HS + d] = h0;
    h0 = fmaf(cl, h0, sv[seg]);
  }
}

// ---------------- Fused: scan_c+normalize (blocks 0..383) | vbuild_t (384..1151) ----
__global__ __launch_bounds__(256) void scanc_vbuild(const float* __restrict__ la_coef,
                                                    const float* __restrict__ kernel_beta,
                                                    const float* __restrict__ carryin,
                                                    const unsigned short* __restrict__ uxv,
                                                    const float* __restrict__ v_coef,
                                                    const float* __restrict__ value_beta,
                                                    __hip_bfloat16* __restrict__ kb16,
                                                    __hip_bfloat16* __restrict__ vt) {
  __shared__ __hip_bfloat16 sm[64][73];
  const int NBC = B_ * NH * NSEG / 4;   // 384 scan_c blocks
  if ((int)blockIdx.x < NBC) {
    int cid = blockIdx.x * 4 + (threadIdx.x >> 6);
    int d   = threadIdx.x & 63;
    int seg = cid & (NSEG - 1);
    int bh  = cid >> 6;
    int h   = bh % NH;
    int b   = bh / NH;
    float c  = la_coef[h];
    float oc = 1.f - c;
    float bk = __expf(fminf(kernel_beta[h] * 10.f, 5.f));
    int t0 = seg * SEGLEN;
    const unsigned short* up = uxv + ((size_t)b * T_ + t0) * CX + h * HS + d;
    __hip_bfloat16* op = kb16 + ((size_t)bh * T_ + t0) * HS + d;
    float uv[SEGLEN];
#pragma unroll
    for (int i = 0; i < SEGLEN; ++i) uv[i] = b2f(up[(size_t)i * CX]);
    float y = carryin[(size_t)cid * HS + d];
    for (int i = 0; i < SEGLEN; ++i) {
      y = fmaf(c, y, oc * uv[i]);
      float ss = y * y;
#pragma unroll
      for (int off = 1; off < 64; off <<= 1) ss += __shfl_xor(ss, off, 64);
      float scale = bk / (sqrtf(ss) + 1e-6f);
      op[(size_t)i * HS] = __float2bfloat16(y * scale);
    }
  } else {
    int idx = blockIdx.x - NBC;
    int t0 = (idx & 31) * 64;
    int bh = idx >> 5;
    int h = bh % NH, b = bh / NH;
    int w = threadIdx.x >> 6, lane = threadIdx.x & 63;
    float vc = v_coef[h];
    float vb = __expf(fminf(value_beta[h] * 10.f, 5.f));
    for (int i = 0; i < 16; ++i) {
      int tl = w * 16 + i;
      int t = t0 + tl;
      const unsigned short* xp = uxv + ((size_t)b * T_ + t) * CX + 768 + h * HS + lane;
      float x0 = b2f(*xp);
      float x1 = (t + 1 < T_) ? b2f(xp[CX]) : 0.f;
      float vf = (1.f - vc) * x1 + vc * x0;
      float ss = vf * vf;
#pragma unroll
      for (int off = 1; off < 64; off <<= 1) ss += __shfl_xor(ss, off, 64);
      sm[tl][lane] = __float2bfloat16(vf * vb / (sqrtf(ss) + 1e-6f));
    }
    __syncthreads();
    int d = threadIdx.x >> 3;
    int c = threadIdx.x & 7;
    for (int i = 0; i < 2; ++i) {
      int dd = d + i * 32;
      short8 v;
#pragma unroll
      for (int k = 0; k < 8; ++k)
        v[k] = (short)((const unsigned short*)&sm[c * 8 + k][dd])[0];
      *(short8*)((unsigned short*)vt + ((size_t)bh * HS + dd) * T_ + t0 + c * 8) = v;
    }
  }
}

// ---------------- attention v11b: work-mixing it-permutation for co-resident grid ---
// Grid is fully co-resident (768 blocks, 3/CU) -> no dynamic rebalancing. Alternate
// heavy/light mapping it = qt&1 ? (qt-1)/2 : 31-qt/2 gives each CU a mixed triple
// (per-CU work spread ~1.25x vs ~31x with monotone mapping). Inner loop = attn11.
__global__ __launch_bounds__(256, 2) void attn11(const __hip_bfloat16* __restrict__ Kg,
                                                 const __hip_bfloat16* __restrict__ Vtg,
                                                 const float* __restrict__ kernel_beta,
                                                 __hip_bfloat16* __restrict__ Y) {
  __shared__ __align__(16) char lds[41984];  // 2 x 20KB combine bufs + 1KB lsum
  const int bh = blockIdx.x;
  const int b = bh / NH, h = bh % NH;
  const int w = threadIdx.x >> 6, lane = threadIdx.x & 63;
  const int l31 = lane & 31, lg2 = lane >> 5;
  const int qt = blockIdx.y;
  const int it = (qt & 1) ? ((qt - 1) >> 1) : (31 - (qt >> 1));  // 31,0,30,1,...,16,15
  const int qb0 = 1 + it * 64;
  const int NT32 = 2 * it + 2;               // 32-key tiles covering j <= qb0+62
  const int NTU = NT32 - 2;                  // kt < NTU: fully unmasked
  float bk = __expf(fminf(kernel_beta[h] * 10.f, 5.f));
  const float L2E = 1.4426950408889634f;
  const float m0l = bk * bk * L2E;
  const unsigned short* Kh = (const unsigned short*)Kg + (size_t)bh * T_ * HS;
  const unsigned short* Vh = (const unsigned short*)Vtg + (size_t)bh * HS * T_;
  unsigned short* Yh = (unsigned short*)Y + (size_t)b * T_ * C_ + h * HS;

  if (it == 0 && w == 0) Yh[lane] = 0;  // t=0 row zero

  short8 qf[2][4];
#pragma unroll
  for (int qs = 0; qs < 2; ++qs) {
    int tqc = qb0 + qs * 32 + l31;
    if (tqc > T_ - 1) tqc = T_ - 1;
#pragma unroll
    for (int s = 0; s < 4; ++s)
      qf[qs][s] = *(const short8*)(Kh + (size_t)tqc * HS + s * 16 + lg2 * 8);
  }

  f32x16 zero16 = {0.f};
  f32x16 accO[2][2];
#pragma unroll
  for (int qs = 0; qs < 2; ++qs)
#pragma unroll
    for (int ds = 0; ds < 2; ++ds) accO[qs][ds] = zero16;
  float lsum[2] = {0.f, 0.f};

#define LOADT(KF, VF, j0)                                                             \
  {                                                                                   \
    _Pragma("unroll")                                                                 \
    for (int s = 0; s < 4; ++s)                                                       \
      KF[s] = *(const short8*)(Kh + (size_t)((j0) + l31) * HS + s * 16 + lg2 * 8);    \
    _Pragma("unroll")                                                                 \
    for (int ds = 0; ds < 2; ++ds)                                                    \
      _Pragma("unroll")                                                               \
      for (int s2 = 0; s2 < 2; ++s2)                                                  \
        VF[ds][s2] = *(const short8*)(Vh + (size_t)(ds * 32 + l31) * T_ + (j0) +      \
                                      s2 * 16 + lg2 * 8);                             \
  }

#define PV_STEP(VF, qs)                                                               \
  {                                                                                   \
    __builtin_amdgcn_s_setprio(1);                                                    \
    _Pragma("unroll")                                                                 \
    for (int ds = 0; ds < 2; ++ds) {                                                  \
      accO[qs][ds] = __builtin_amdgcn_mfma_f32_32x32x16_bf16(VF[ds][0], PB0,          \
                                                             accO[qs][ds], 0, 0, 0);  \
      accO[qs][ds] = __builtin_amdgcn_mfma_f32_32x32x16_bf16(VF[ds][1], PB1,          \
                                                             accO[qs][ds], 0, 0, 0);  \
    }                                                                                 \
    __builtin_amdgcn_s_setprio(0);                                                    \
  }

#define PACK_P()                                                                      \
  uint2v g00 = __builtin_amdgcn_permlane32_swap(cvtpk(p[0], p[1]),                    \
                                                cvtpk(p[4], p[5]), false, false);     \
  uint2v g01 = __builtin_amdgcn_permlane32_swap(cvtpk(p[2], p[3]),                    \
                                                cvtpk(p[6], p[7]), false, false);     \
  uint2v g10 = __builtin_amdgcn_permlane32_swap(cvtpk(p[8], p[9]),                    \
                                                cvtpk(p[12], p[13]), false, false);   \
  uint2v g11 = __builtin_amdgcn_permlane32_swap(cvtpk(p[10], p[11]),                  \
                                                cvtpk(p[14], p[15]), false, false);   \
  uint4v pb0v, pb1v;                                                                  \
  pb0v.x = g00.x; pb0v.y = g01.x; pb0v.z = g00.y; pb0v.w = g01.y;                     \
  pb1v.x = g10.x; pb1v.y = g11.x; pb1v.z = g10.y; pb1v.w = g11.y;                     \
  short8 PB0 = __builtin_bit_cast(short8, pb0v);                                      \
  short8 PB1 = __builtin_bit_cast(short8, pb1v);

#define COMPUTE_U(KF, VF)                                                             \
  {                                                                                   \
    _Pragma("unroll")                                                                 \
    for (int qs = 0; qs < 2; ++qs) {                                                  \
      f32x16 S = zero16;                                                              \
      __builtin_amdgcn_s_setprio(1);                                                  \
      _Pragma("unroll")                                                               \
      for (int s = 0; s < 4; ++s)                                                     \
        S = __builtin_amdgcn_mfma_f32_32x32x16_bf16(KF[s], qf[qs][s], S, 0, 0, 0);    \
      __builtin_amdgcn_s_setprio(0);                                                  \
      float p[16];                                                                    \
      _Pragma("unroll")                                                               \
      for (int r = 0; r < 16; ++r) {                                                  \
        p[r] = exp2f(fmaf(S[r], L2E, -m0l));                                          \
        lsum[qs] += p[r];                                                             \
      }                                                                               \
      PACK_P();                                                                       \
      PV_STEP(VF, qs);                                                                \
    }                                                                                 \
  }

#define COMPUTE_M(KF, VF, ktv)                                                        \
  {                                                                                   \
    const int jb = (ktv)*32 + 4 * lg2;                                                \
    _Pragma("unroll")                                                                 \
    for (int qs = 0; qs < 2; ++qs) {                                                  \
      const int tqq = qb0 + qs * 32 + l31;                                            \
      f32x16 S = zero16;                                                              \
      _Pragma("unroll")                                                               \
      for (int s = 0; s < 4; ++s)                                                     \
        S = __builtin_amdgcn_mfma_f32_32x32x16_bf16(KF[s], qf[qs][s], S, 0, 0, 0);    \
      float p[16];                                                                    \
      _Pragma("unroll")                                                               \
      for (int r = 0; r < 16; ++r) {                                                  \
        int jg = jb + (r & 3) + 8 * (r >> 2);                                         \
        p[r] = (jg < tqq) ? exp2f(fmaf(S[r], L2E, -m0l)) : 0.f;                       \
        lsum[qs] += p[r];                                                             \
      }                                                                               \
      PACK_P();                                                                       \
      PV_STEP(VF, qs);                                                                \
    }                                                                                 \
  }

  short8 kfA[4], vfA[2][2], kfB[4], vfB[2][2];
  int kt = w;
  if (kt < NTU) {
    LOADT(kfA, vfA, kt * 32);
    while (true) {
      if (kt + 4 < NTU) LOADT(kfB, vfB, (kt + 4) * 32);
      COMPUTE_U(kfA, vfA);
      kt += 4;
      if (kt >= NTU) break;
      if (kt + 4 < NTU) LOADT(kfA, vfA, (kt + 4) * 32);
      COMPUTE_U(kfB, vfB);
      kt += 4;
      if (kt >= NTU) break;
    }
  }
  for (; kt < NT32; kt += 4) {
    LOADT(kfA, vfA, kt * 32);
    COMPUTE_M(kfA, vfA, kt);
  }

#pragma unroll
  for (int qs = 0; qs < 2; ++qs) lsum[qs] += __shfl_xor(lsum[qs], 32, 64);

  // ---- tree combine over waves; rows at 80B stride (8-way max bank aliasing) ------
  float* LR = (float*)(lds + 40960);  // [w][qs][l31]
  __syncthreads();
  if (w >= 2) {
    float* PB = (float*)(lds + (size_t)(w - 2) * 20480);
#pragma unroll
    for (int qs = 0; qs < 2; ++qs)
#pragma unroll
      for (int ds = 0; ds < 2; ++ds) {
        float* rb = PB + ((qs * 2 + ds) * 64 + lane) * 20;
#pragma unroll
        for (int c = 0; c < 4; ++c)
          *(f32x4*)(rb + c * 4) = (f32x4){accO[qs][ds][c * 4 + 0], accO[qs][ds][c * 4 + 1],
                                          accO[qs][ds][c * 4 + 2], accO[qs][ds][c * 4 + 3]};
      }
  }
#pragma unroll
  for (int qs = 0; qs < 2; ++qs) LR[(w * 2 + qs) * 32 + l31] = lsum[qs];
  __syncthreads();
  if (w < 2) {
    float* PB = (float*)(lds + (size_t)w * 20480);
#pragma unroll
    for (int qs = 0; qs < 2; ++qs)
#pragma unroll
      for (int ds = 0; ds < 2; ++ds) {
        float* rb = PB + ((qs * 2 + ds) * 64 + lane) * 20;
#pragma unroll
        for (int c = 0; c < 4; ++c) {
          f32x4 o = *(f32x4*)(rb + c * 4);
          accO[qs][ds][c * 4 + 0] += o[0]; accO[qs][ds][c * 4 + 1] += o[1];
          accO[qs][ds][c * 4 + 2] += o[2]; accO[qs][ds][c * 4 + 3] += o[3];
        }
      }
    if (w == 1) {
#pragma unroll
      for (int qs = 0; qs < 2; ++qs)
#pragma unroll
        for (int ds = 0; ds < 2; ++ds) {
          float* rb = PB + ((qs * 2 + ds) * 64 + lane) * 20;
#pragma unroll
          for (int c = 0; c < 4; ++c)
            *(f32x4*)(rb + c * 4) = (f32x4){accO[qs][ds][c * 4 + 0], accO[qs][ds][c * 4 + 1],
                                            accO[qs][ds][c * 4 + 2], accO[qs][ds][c * 4 + 3]};
        }
    }
  }
  __syncthreads();
  if (w == 0) {
    float* PB1 = (float*)(lds + 20480);
#pragma unroll
    for (int qs = 0; qs < 2; ++qs) {
#pragma unroll
      for (int ds = 0; ds < 2; ++ds) {
        float* rb = PB1 + ((qs * 2 + ds) * 64 + lane) * 20;
#pragma unroll
        for (int c = 0; c < 4; ++c) {
          f32x4 o = *(f32x4*)(rb + c * 4);
          accO[qs][ds][c * 4 + 0] += o[0]; accO[qs][ds][c * 4 + 1] += o[1];
          accO[qs][ds][c * 4 + 2] += o[2]; accO[qs][ds][c * 4 + 3] += o[3];
        }
      }
      float tot = LR[(0 * 2 + qs) * 32 + l31] + LR[(1 * 2 + qs) * 32 + l31] +
                  LR[(2 * 2 + qs) * 32 + l31] + LR[(3 * 2 + qs) * 32 + l31];
      float inv = 1.f / tot;
      int tq = qb0 + qs * 32 + l31;
      if (tq < T_) {
        unsigned short* yp = Yh + (size_t)tq * C_;
#pragma unroll
        for (int ds = 0; ds < 2; ++ds)
#pragma unroll
          for (int r = 0; r < 16; r += 2) {
            int d = ds * 32 + (r & 3) + 8 * (r >> 2) + 4 * lg2;
            unsigned u = cvtpk(accO[qs][ds][r] * inv, accO[qs][ds][r + 1] * inv);
            *(unsigned*)(yp + d) = u;
          }
      }
    }
  }
#undef LOADT
#undef COMPUTE_U
#undef COMPUTE_M
#undef PACK_P
#undef PV_STEP
}

extern "C" void kernel_launch(void* const* d_in, const int* in_sizes, int n_in,
                              void* d_out, int out_size, void* d_ws, size_t ws_size,
                              hipStream_t stream) {
  const float* x          = (const float*)d_in[0];
  const float* W_la       = (const float*)d_in[1];
  const float* la_coef    = (const float*)d_in[2];
  const float* W_v        = (const float*)d_in[3];
  const float* v_coef     = (const float*)d_in[4];
  const float* kernel_bet = (const float*)d_in[5];
  const float* value_bet  = (const float*)d_in[6];
  const float* W_proj     = (const float*)d_in[7];
  float* out = (float*)d_out;

  char* ws = (char*)d_ws;
  const size_t NTOK = (size_t)B_ * T_ * C_;            // 3,145,728
  const size_t NSEGTOT = (size_t)B_ * NH * NSEG * HS;  // 98,304
  unsigned short* uxv = (unsigned short*)ws;                       // (B*T, CX) bf16
  float* segend  = (float*)(ws + (size_t)B_ * T_ * CX * 2);
  float* carryin = segend + NSEGTOT;
  __hip_bfloat16* kb16 = (__hip_bfloat16*)(carryin + NSEGTOT);     // (B,NH,T,HS)
  __hip_bfloat16* vt16 = kb16 + NTOK;                              // (B,NH,HS,T)
  __hip_bfloat16* xb   = vt16 + NTOK;                              // (B*T,C) bf16
  __hip_bfloat16* Wcat = xb + NTOK;                                // (1536,768) bf16
  __hip_bfloat16* Wpb  = Wcat + (size_t)CX * C_;                   // (768,768) bf16
  __hip_bfloat16* yb   = xb;  // alias: xb dead after gemm1

  const int M = B_ * T_;

  cast_all<<<2048, 256, 0, stream>>>(x, W_la, W_v, W_proj, xb, Wcat, Wpb);

  gemm_bf16<64, true><<<dim3(M / 64, CX / 128), 256, 0, stream>>>(xb, Wcat, uxv, M, CX, C_);

  scan_seg<<<dim3(B_ * NH * NSEG / 4), 256, 0, stream>>>(uxv, la_coef, segend);
  scan_b<<<dim3((B_ * NH * HS + 255) / 256), 256, 0, stream>>>(la_coef, segend, carryin);
  scanc_vbuild<<<dim3(B_ * NH * NSEG / 4 + 32 * B_ * NH), 256, 0, stream>>>(
      la_coef, kernel_bet, carryin, uxv, v_coef, value_bet, kb16, vt16);

  attn11<<<dim3(B_ * NH, 32), 256, 0, stream>>>(kb16, vt16, kernel_bet, yb);

  gemm_bf16<64, false><<<dim3(M / 64, C_ / 128), 256, 0, stream>>>(yb, Wpb, out, M, C_, C_);
}

// Round 19
// 102.986 us; speedup vs baseline: 1.0069x; 1.0069x over previous
//
#include <hip/hip_runtime.h>
#include <hip/hip_bf16.h>
#include <math.h>

#define B_   2
#define T_   2048
#define C_   768
#define NH   12
#define HS   64
#define NSEG 64
#define SEGLEN 32
#define CX   1536   // uxv row stride (u | xv)
#define NITEMS (B_ * NH * 32)   // 768 attention work items

typedef __attribute__((ext_vector_type(8))) short short8;
typedef __attribute__((ext_vector_type(4))) short short4v;
typedef __attribute__((ext_vector_type(4))) float f32x4;
typedef __attribute__((ext_vector_type(16))) float f32x16;
typedef __attribute__((ext_vector_type(2))) unsigned int uint2v;
typedef __attribute__((ext_vector_type(4))) unsigned int uint4v;

static __device__ inline unsigned short f2b(float f) {
  __hip_bfloat16 h = __float2bfloat16(f);
  unsigned short u;
  __builtin_memcpy(&u, &h, 2);
  return u;
}
static __device__ inline float b2f(unsigned short u) {
  unsigned int x = ((unsigned int)u) << 16;
  float f;
  __builtin_memcpy(&f, &x, 4);
  return f;
}
static __device__ inline unsigned cvtpk(float a, float b) {
  unsigned r;
  asm("v_cvt_pk_bf16_f32 %0, %1, %2" : "=v"(r) : "v"(a), "v"(b));
  return r;
}

#define GLOAD_LDS16(gp, lp)                                                        \
  __builtin_amdgcn_global_load_lds((const __attribute__((address_space(1))) void*)(gp), \
                                   (__attribute__((address_space(3))) void*)(lp), 16, 0, 0)

// ---------------- fused f32 -> bf16 casts (x, W_la|W_v -> Wcat, W_proj) -------------
__global__ __launch_bounds__(256) void cast_all(const float* __restrict__ x,
                                                const float* __restrict__ wla,
                                                const float* __restrict__ wv,
                                                const float* __restrict__ wp,
                                                __hip_bfloat16* __restrict__ xb,
                                                __hip_bfloat16* __restrict__ wcat,
                                                __hip_bfloat16* __restrict__ wpb) {
  const int NX4 = (B_ * T_ * C_) / 4;     // 786432
  const int NW4 = (C_ * C_) / 4;          // 147456
  const int TOT = NX4 + 3 * NW4;
  int i = blockIdx.x * 256 + threadIdx.x;
  int st = gridDim.x * 256;
  for (; i < TOT; i += st) {
    const float* s;
    unsigned short* d;
    if (i < NX4) { s = x + (size_t)i * 4; d = (unsigned short*)xb + (size_t)i * 4; }
    else if (i < NX4 + NW4) { int j = i - NX4; s = wla + (size_t)j * 4; d = (unsigned short*)wcat + (size_t)j * 4; }
    else if (i < NX4 + 2 * NW4) { int j = i - NX4 - NW4; s = wv + (size_t)j * 4; d = (unsigned short*)wcat + (size_t)(C_ * C_) + (size_t)j * 4; }
    else { int j = i - NX4 - 2 * NW4; s = wp + (size_t)j * 4; d = (unsigned short*)wpb + (size_t)j * 4; }
    float4 v = *(const float4*)s;
    short4v o;
    o.x = (short)f2b(v.x); o.y = (short)f2b(v.y); o.z = (short)f2b(v.z); o.w = (short)f2b(v.w);
    *(short4v*)d = o;
  }
}

// ---------------- bf16 MFMA GEMM: C[m,n] = sum_k A[m,k] * Bw[n,k] -------------------
template <int BM, bool OB16>
__global__ __launch_bounds__(256) void gemm_bf16(const __hip_bfloat16* __restrict__ A,
                                                 const __hip_bfloat16* __restrict__ Bw,
                                                 void* __restrict__ Cv,
                                                 int M, int N, int K) {
  __shared__ __hip_bfloat16 As[BM * 64];
  __shared__ __hip_bfloat16 Bs[128 * 64];
  const int tid = threadIdx.x;
  const int w = tid >> 6, lane = tid & 63;
  const int bm = blockIdx.x * BM, bn = blockIdx.y * 128;
  const int q16 = lane & 15, lg = lane >> 4;

  constexpr int NACC = (BM == 128) ? 4 : 2;
  f32x4 acc[4][NACC];
#pragma unroll
  for (int i = 0; i < 4; ++i)
#pragma unroll
    for (int j = 0; j < NACC; ++j) acc[i][j] = (f32x4){0.f, 0.f, 0.f, 0.f};

  const int srow = (lane >> 3);
  const int soff0 = (lane & 7) * 16;
  const int sw = (lane & 7) << 4;
  constexpr int ACH = BM / 8;
  constexpr int CPW = (ACH + 16) / 4;

  for (int k0 = 0; k0 < K; k0 += 64) {
    __syncthreads();
#pragma unroll
    for (int c = 0; c < CPW; ++c) {
      int gc = w * CPW + c;
      int isB = gc >= ACH;
      int ci = isB ? gc - ACH : gc;
      int row = ci * 8 + srow;
      int soff = soff0 ^ ((row & 7) << 4);
      const __hip_bfloat16* gp =
          (isB ? Bw + (size_t)(bn + row) * K : A + (size_t)(bm + row) * K) + k0 + (soff >> 1);
      __hip_bfloat16* lp = (isB ? Bs : As) + ci * 512;
      GLOAD_LDS16(gp, lp);
    }
    __syncthreads();
#pragma unroll
    for (int ks = 0; ks < 2; ++ks) {
      short8 af[4], bf[NACC];
      const int colb = ks * 64 + lg * 16;
#pragma unroll
      for (int i = 0; i < 4; ++i) {
        int ra = (BM == 128) ? ((w >> 1) * 64 + i * 16 + q16) : (i * 16 + q16);
        af[i] = *(const short8*)((const char*)As + ra * 128 + (colb ^ sw));
      }
#pragma unroll
      for (int j = 0; j < NACC; ++j) {
        int rb = (BM == 128) ? ((w & 1) * 64 + j * 16 + q16) : (w * 32 + j * 16 + q16);
        bf[j] = *(const short8*)((const char*)Bs + rb * 128 + (colb ^ sw));
      }
#pragma unroll
      for (int i = 0; i < 4; ++i)
#pragma unroll
        for (int j = 0; j < NACC; ++j)
          acc[i][j] = __builtin_amdgcn_mfma_f32_16x16x32_bf16(af[i], bf[j], acc[i][j], 0, 0, 0);
    }
  }
#pragma unroll
  for (int i = 0; i < 4; ++i) {
#pragma unroll
    for (int r = 0; r < 4; ++r) {
      int m = (BM == 128) ? (bm + (w >> 1) * 64 + i * 16 + lg * 4 + r)
                          : (bm + i * 16 + lg * 4 + r);
      int nb = (BM == 128) ? (bn + (w & 1) * 64 + q16) : (bn + w * 32 + q16);
      if (OB16) {
        unsigned short* cp = (unsigned short*)Cv + (size_t)m * N + nb;
#pragma unroll
        for (int j = 0; j < NACC; ++j) cp[j * 16] = f2b(acc[i][j][r]);
      } else {
        float* cp = (float*)Cv + (size_t)m * N + nb;
#pragma unroll
        for (int j = 0; j < NACC; ++j) cp[j * 16] = acc[i][j][r];
      }
    }
  }
}

// ---------------- Scan pass A: segment end-carries (bf16 u, prefetched loads) -------
__global__ __launch_bounds__(256) void scan_seg(const unsigned short* __restrict__ uxv,
                                                const float* __restrict__ la_coef,
                                                float* __restrict__ segend) {
  int cid = blockIdx.x * 4 + (threadIdx.x >> 6);  // bh*NSEG + seg
  int d   = threadIdx.x & 63;
  int seg = cid & (NSEG - 1);
  int bh  = cid >> 6;
  int h   = bh % NH;
  int b   = bh / NH;
  float c  = la_coef[h];
  float oc = 1.f - c;
  int t0 = seg * SEGLEN;
  const unsigned short* up = uxv + ((size_t)b * T_ + t0) * CX + h * HS + d;
  float uv[SEGLEN];
#pragma unroll
  for (int i = 0; i < SEGLEN; ++i) uv[i] = b2f(up[(size_t)i * CX]);
  float y = 0.f;
#pragma unroll
  for (int i = 0; i < SEGLEN; ++i) y = fmaf(c, y, oc * uv[i]);
  segend[(size_t)cid * HS + d] = y;
}

// ---------------- Scan pass B: combine segment carries (prefetched) -----------------
__global__ __launch_bounds__(256) void scan_b(const float* __restrict__ la_coef,
                                              const float* __restrict__ segend,
                                              float* __restrict__ carryin) {
  int s = blockIdx.x * 256 + threadIdx.x;  // (b,h,d)
  if (s >= B_ * NH * HS) return;
  int d  = s & 63;
  int bh = s >> 6;
  int h  = bh % NH;
  float c = la_coef[h];
  float cl = c;
#pragma unroll
  for (int i = 0; i < 5; ++i) cl *= cl;  // c^32
  float sv[NSEG];
#pragma unroll
  for (int seg = 0; seg < NSEG; ++seg)
    sv[seg] = segend[(size_t)(bh * NSEG + seg) * HS + d];
  float h0 = 0.f;
#pragma unroll
  for (int seg = 0; seg < NSEG; ++seg) {
    carryin[(size_t)(bh * NSEG + seg) * HS + d] = h0;
    h0 = fmaf(cl, h0, sv[seg]);
  }
}

// ---------------- Fused: scan_c+normalize | vbuild_t; also resets attn queue ctr ----
__global__ __launch_bounds__(256) void scanc_vbuild(const float* __restrict__ la_coef,
                                                    const float* __restrict__ kernel_beta,
                                                    const float* __restrict__ carryin,
                                                    const unsigned short* __restrict__ uxv,
                                                    const float* __restrict__ v_coef,
                                                    const float* __restrict__ value_beta,
                                                    __hip_bfloat16* __restrict__ kb16,
                                                    __hip_bfloat16* __restrict__ vt,
                                                    int* __restrict__ ctr) {
  __shared__ __hip_bfloat16 sm[64][73];
  if (blockIdx.x == 0 && threadIdx.x == 0) *ctr = 0;  // reset attn work queue
  const int NBC = B_ * NH * NSEG / 4;   // 384 scan_c blocks
  if ((int)blockIdx.x < NBC) {
    int cid = blockIdx.x * 4 + (threadIdx.x >> 6);
    int d   = threadIdx.x & 63;
    int seg = cid & (NSEG - 1);
    int bh  = cid >> 6;
    int h   = bh % NH;
    int b   = bh / NH;
    float c  = la_coef[h];
    float oc = 1.f - c;
    float bk = __expf(fminf(kernel_beta[h] * 10.f, 5.f));
    int t0 = seg * SEGLEN;
    const unsigned short* up = uxv + ((size_t)b * T_ + t0) * CX + h * HS + d;
    __hip_bfloat16* op = kb16 + ((size_t)bh * T_ + t0) * HS + d;
    float uv[SEGLEN];
#pragma unroll
    for (int i = 0; i < SEGLEN; ++i) uv[i] = b2f(up[(size_t)i * CX]);
    float y = carryin[(size_t)cid * HS + d];
    for (int i = 0; i < SEGLEN; ++i) {
      y = fmaf(c, y, oc * uv[i]);
      float ss = y * y;
#pragma unroll
      for (int off = 1; off < 64; off <<= 1) ss += __shfl_xor(ss, off, 64);
      float scale = bk / (sqrtf(ss) + 1e-6f);
      op[(size_t)i * HS] = __float2bfloat16(y * scale);
    }
  } else {
    int idx = blockIdx.x - NBC;
    int t0 = (idx & 31) * 64;
    int bh = idx >> 5;
    int h = bh % NH, b = bh / NH;
    int w = threadIdx.x >> 6, lane = threadIdx.x & 63;
    float vc = v_coef[h];
    float vb = __expf(fminf(value_beta[h] * 10.f, 5.f));
    for (int i = 0; i < 16; ++i) {
      int tl = w * 16 + i;
      int t = t0 + tl;
      const unsigned short* xp = uxv + ((size_t)b * T_ + t) * CX + 768 + h * HS + lane;
      float x0 = b2f(*xp);
      float x1 = (t + 1 < T_) ? b2f(xp[CX]) : 0.f;
      float vf = (1.f - vc) * x1 + vc * x0;
      float ss = vf * vf;
#pragma unroll
      for (int off = 1; off < 64; off <<= 1) ss += __shfl_xor(ss, off, 64);
      sm[tl][lane] = __float2bfloat16(vf * vb / (sqrtf(ss) + 1e-6f));
    }
    __syncthreads();
    int d = threadIdx.x >> 3;
    int c = threadIdx.x & 7;
    for (int i = 0; i < 2; ++i) {
      int dd = d + i * 32;
      short8 v;
#pragma unroll
      for (int k = 0; k < 8; ++k)
        v[k] = (short)((const unsigned short*)&sm[c * 8 + k][dd])[0];
      *(short8*)((unsigned short*)vt + ((size_t)bh * HS + dd) * T_ + t0 + c * 8) = v;
    }
  }
}

// ---------------- attention v13: persistent blocks + dynamic work queue -------------
// 768 items = (bh, it row-block), heavy-first (it = 31 - idx/24). 512 persistent
// blocks (2/CU) pull items via global atomicAdd -> per-CU work self-balances
// (~99 tiles/CU vs 130 worst-case static). Item body = attn11 (32x32 MFMA,
// in-register P via cvt_pk+permlane32_swap, unmasked hot loop, 0 main-loop LDS).
__global__ __launch_bounds__(256, 2) void attn13(const __hip_bfloat16* __restrict__ Kg,
                                                 const __hip_bfloat16* __restrict__ Vtg,
                                                 const float* __restrict__ kernel_beta,
                                                 __hip_bfloat16* __restrict__ Y,
                                                 int* __restrict__ ctr) {
  __shared__ __align__(16) char lds[41984];  // 2 x 20KB combine bufs + 1KB lsum
  __shared__ int sItem;
  const int w = threadIdx.x >> 6, lane = threadIdx.x & 63;
  const int l31 = lane & 31, lg2 = lane >> 5;
  const float L2E = 1.4426950408889634f;

  for (;;) {
    if (threadIdx.x == 0) sItem = atomicAdd(ctr, 1);
    __syncthreads();
    const int idx = sItem;
    if (idx >= NITEMS) break;
    const int it = 31 - idx / (B_ * NH);       // heavy-first
    const int bh = idx % (B_ * NH);
    const int b = bh / NH, h = bh % NH;
    const int qb0 = 1 + it * 64;
    const int NT32 = 2 * it + 2;               // 32-key tiles covering j <= qb0+62
    const int NTU = NT32 - 2;                  // kt < NTU: fully unmasked
    float bk = __expf(fminf(kernel_beta[h] * 10.f, 5.f));
    const float m0l = bk * bk * L2E;
    const unsigned short* Kh = (const unsigned short*)Kg + (size_t)bh * T_ * HS;
    const unsigned short* Vh = (const unsigned short*)Vtg + (size_t)bh * HS * T_;
    unsigned short* Yh = (unsigned short*)Y + (size_t)b * T_ * C_ + h * HS;

    if (it == 0 && w == 0) Yh[lane] = 0;  // t=0 row zero (once per bh)

    short8 qf[2][4];
#pragma unroll
    for (int qs = 0; qs < 2; ++qs) {
      int tqc = qb0 + qs * 32 + l31;
      if (tqc > T_ - 1) tqc = T_ - 1;
#pragma unroll
      for (int s = 0; s < 4; ++s)
        qf[qs][s] = *(const short8*)(Kh + (size_t)tqc * HS + s * 16 + lg2 * 8);
    }

    f32x16 zero16 = {0.f};
    f32x16 accO[2][2];
#pragma unroll
    for (int qs = 0; qs < 2; ++qs)
#pragma unroll
      for (int ds = 0; ds < 2; ++ds) accO[qs][ds] = zero16;
    float lsum[2] = {0.f, 0.f};

#define LOADT(KF, VF, j0)                                                             \
    {                                                                                 \
      _Pragma("unroll")                                                               \
      for (int s = 0; s < 4; ++s)                                                     \
        KF[s] = *(const short8*)(Kh + (size_t)((j0) + l31) * HS + s * 16 + lg2 * 8);  \
      _Pragma("unroll")                                                               \
      for (int ds = 0; ds < 2; ++ds)                                                  \
        _Pragma("unroll")                                                             \
        for (int s2 = 0; s2 < 2; ++s2)                                                \
          VF[ds][s2] = *(const short8*)(Vh + (size_t)(ds * 32 + l31) * T_ + (j0) +    \
                                        s2 * 16 + lg2 * 8);                           \
    }

#define PV_STEP(VF, qs)                                                               \
    {                                                                                 \
      __builtin_amdgcn_s_setprio(1);                                                  \
      _Pragma("unroll")                                                               \
      for (int ds = 0; ds < 2; ++ds) {                                                \
        accO[qs][ds] = __builtin_amdgcn_mfma_f32_32x32x16_bf16(VF[ds][0], PB0,        \
                                                               accO[qs][ds], 0, 0, 0);\
        accO[qs][ds] = __builtin_amdgcn_mfma_f32_32x32x16_bf16(VF[ds][1], PB1,        \
                                                               accO[qs][ds], 0, 0, 0);\
      }                                                                               \
      __builtin_amdgcn_s_setprio(0);                                                  \
    }

#define PACK_P()                                                                      \
    uint2v g00 = __builtin_amdgcn_permlane32_swap(cvtpk(p[0], p[1]),                  \
                                                  cvtpk(p[4], p[5]), false, false);   \
    uint2v g01 = __builtin_amdgcn_permlane32_swap(cvtpk(p[2], p[3]),                  \
                                                  cvtpk(p[6], p[7]), false, false);   \
    uint2v g10 = __builtin_amdgcn_permlane32_swap(cvtpk(p[8], p[9]),                  \
                                                  cvtpk(p[12], p[13]), false, false); \
    uint2v g11 = __builtin_amdgcn_permlane32_swap(cvtpk(p[10], p[11]),                \
                                                  cvtpk(p[14], p[15]), false, false); \
    uint4v pb0v, pb1v;                                                                \
    pb0v.x = g00.x; pb0v.y = g01.x; pb0v.z = g00.y; pb0v.w = g01.y;                   \
    pb1v.x = g10.x; pb1v.y = g11.x; pb1v.z = g10.y; pb1v.w = g11.y;                   \
    short8 PB0 = __builtin_bit_cast(short8, pb0v);                                    \
    short8 PB1 = __builtin_bit_cast(short8, pb1v);

#define COMPUTE_U(KF, VF)                                                             \
    {                                                                                 \
      _Pragma("unroll")                                                               \
      for (int qs = 0; qs < 2; ++qs) {                                                \
        f32x16 S = zero16;                                                            \
        __builtin_amdgcn_s_setprio(1);                                                \
        _Pragma("unroll")                                                             \
        for (int s = 0; s < 4; ++s)                                                   \
          S = __builtin_amdgcn_mfma_f32_32x32x16_bf16(KF[s], qf[qs][s], S, 0, 0, 0);  \
        __builtin_amdgcn_s_setprio(0);                                                \
        float p[16];                                                                  \
        _Pragma("unroll")                                                             \
        for (int r = 0; r < 16; ++r) {                                                \
          p[r] = exp2f(fmaf(S[r], L2E, -m0l));                                        \
          lsum[qs] += p[r];                                                           \
        }                                                                             \
        PACK_P();                                                                     \
        PV_STEP(VF, qs);                                                              \
      }                                                                               \
    }

#define COMPUTE_M(KF, VF, ktv)                                                        \
    {                                                                                 \
      const int jb = (ktv)*32 + 4 * lg2;                                              \
      _Pragma("unroll")                                                               \
      for (int qs = 0; qs < 2; ++qs) {                                                \
        const int tqq = qb0 + qs * 32 + l31;                                          \
        f32x16 S = zero16;                                                            \
        _Pragma("unroll")                                                             \
        for (int s = 0; s < 4; ++s)                                                   \
          S = __builtin_amdgcn_mfma_f32_32x32x16_bf16(KF[s], qf[qs][s], S, 0, 0, 0);  \
        float p[16];                                                                  \
        _Pragma("unroll")                                                             \
        for (int r = 0; r < 16; ++r) {                                                \
          int jg = jb + (r & 3) + 8 * (r >> 2);                                       \
          p[r] = (jg < tqq) ? exp2f(fmaf(S[r], L2E, -m0l)) : 0.f;                     \
          lsum[qs] += p[r];                                                           \
        }                                                                             \
        PACK_P();                                                                     \
        PV_STEP(VF, qs);                                                              \
      }                                                                               \
    }

    short8 kfA[4], vfA[2][2], kfB[4], vfB[2][2];
    int kt = w;
    if (kt < NTU) {
      LOADT(kfA, vfA, kt * 32);
      while (true) {
        if (kt + 4 < NTU) LOADT(kfB, vfB, (kt + 4) * 32);
        COMPUTE_U(kfA, vfA);
        kt += 4;
        if (kt >= NTU) break;
        if (kt + 4 < NTU) LOADT(kfA, vfA, (kt + 4) * 32);
        COMPUTE_U(kfB, vfB);
        kt += 4;
        if (kt >= NTU) break;
      }
    }
    for (; kt < NT32; kt += 4) {
      LOADT(kfA, vfA, kt * 32);
      COMPUTE_M(kfA, vfA, kt);
    }

#pragma unroll
    for (int qs = 0; qs < 2; ++qs) lsum[qs] += __shfl_xor(lsum[qs], 32, 64);

    // ---- tree combine over waves; rows at 80B stride ----
    float* LR = (float*)(lds + 40960);  // [w][qs][l31]
    __syncthreads();
    if (w >= 2) {
      float* PB = (float*)(lds + (size_t)(w - 2) * 20480);
#pragma unroll
      for (int qs = 0; qs < 2; ++qs)
#pragma unroll
        for (int ds = 0; ds < 2; ++ds) {
          float* rb = PB + ((qs * 2 + ds) * 64 + lane) * 20;
#pragma unroll
          for (int c = 0; c < 4; ++c)
            *(f32x4*)(rb + c * 4) = (f32x4){accO[qs][ds][c * 4 + 0], accO[qs][ds][c * 4 + 1],
                                            accO[qs][ds][c * 4 + 2], accO[qs][ds][c * 4 + 3]};
        }
    }
#pragma unroll
    for (int qs = 0; qs < 2; ++qs) LR[(w * 2 + qs) * 32 + l31] = lsum[qs];
    __syncthreads();
    if (w < 2) {
      float* PB = (float*)(lds + (size_t)w * 20480);
#pragma unroll
      for (int qs = 0; qs < 2; ++qs)
#pragma unroll
        for (int ds = 0; ds < 2; ++ds) {
          float* rb = PB + ((qs * 2 + ds) * 64 + lane) * 20;
#pragma unroll
          for (int c = 0; c < 4; ++c) {
            f32x4 o = *(f32x4*)(rb + c * 4);
            accO[qs][ds][c * 4 + 0] += o[0]; accO[qs][ds][c * 4 + 1] += o[1];
            accO[qs][ds][c * 4 + 2] += o[2]; accO[qs][ds][c * 4 + 3] += o[3];
          }
        }
      if (w == 1) {
#pragma unroll
        for (int qs = 0; qs < 2; ++qs)
#pragma unroll
          for (int ds = 0; ds < 2; ++ds) {
            float* rb = PB + ((qs * 2 + ds) * 64 + lane) * 20;
#pragma unroll
            for (int c = 0; c < 4; ++c)
              *(f32x4*)(rb + c * 4) = (f32x4){accO[qs][ds][c * 4 + 0], accO[qs][ds][c * 4 + 1],
                                              accO[qs][ds][c * 4 + 2], accO[qs][ds][c * 4 + 3]};
          }
      }
    }
    __syncthreads();
    if (w == 0) {
      float* PB1 = (float*)(lds + 20480);
#pragma unroll
      for (int qs = 0; qs < 2; ++qs) {
#pragma unroll
        for (int ds = 0; ds < 2; ++ds) {
          float* rb = PB1 + ((qs * 2 + ds) * 64 + lane) * 20;
#pragma unroll
          for (int c = 0; c < 4; ++c) {
            f32x4 o = *(f32x4*)(rb + c * 4);
            accO[qs][ds][c * 4 + 0] += o[0]; accO[qs][ds][c * 4 + 1] += o[1];
            accO[qs][ds][c * 4 + 2] += o[2]; accO[qs][ds][c * 4 + 3] += o[3];
          }
        }
        float tot = LR[(0 * 2 + qs) * 32 + l31] + LR[(1 * 2 + qs) * 32 + l31] +
                    LR[(2 * 2 + qs) * 32 + l31] + LR[(3 * 2 + qs) * 32 + l31];
        float inv = 1.f / tot;
        int tq = qb0 + qs * 32 + l31;
        if (tq < T_) {
          unsigned short* yp = Yh + (size_t)tq * C_;
#pragma unroll
          for (int ds = 0; ds < 2; ++ds)
#pragma unroll
            for (int r = 0; r < 16; r += 2) {
              int d = ds * 32 + (r & 3) + 8 * (r >> 2) + 4 * lg2;
              unsigned u = cvtpk(accO[qs][ds][r] * inv, accO[qs][ds][r + 1] * inv);
              *(unsigned*)(yp + d) = u;
            }
        }
      }
    }
    __syncthreads();  // combine buffers + sItem free before next item
#undef LOADT
#undef COMPUTE_U
#undef COMPUTE_M
#undef PACK_P
#undef PV_STEP
  }
}

extern "C" void kernel_launch(void* const* d_in, const int* in_sizes, int n_in,
                              void* d_out, int out_size, void* d_ws, size_t ws_size,
                              hipStream_t stream) {
  const float* x          = (const float*)d_in[0];
  const float* W_la       = (const float*)d_in[1];
  const float* la_coef    = (const float*)d_in[2];
  const float* W_v        = (const float*)d_in[3];
  const float* v_coef     = (const float*)d_in[4];
  const float* kernel_bet = (const float*)d_in[5];
  const float* value_bet  = (const float*)d_in[6];
  const float* W_proj     = (const float*)d_in[7];
  float* out = (float*)d_out;

  char* ws = (char*)d_ws;
  const size_t NTOK = (size_t)B_ * T_ * C_;            // 3,145,728
  const size_t NSEGTOT = (size_t)B_ * NH * NSEG * HS;  // 98,304
  unsigned short* uxv = (unsigned short*)ws;                       // (B*T, CX) bf16
  float* segend  = (float*)(ws + (size_t)B_ * T_ * CX * 2);
  float* carryin = segend + NSEGTOT;
  __hip_bfloat16* kb16 = (__hip_bfloat16*)(carryin + NSEGTOT);     // (B,NH,T,HS)
  __hip_bfloat16* vt16 = kb16 + NTOK;                              // (B,NH,HS,T)
  __hip_bfloat16* xb   = vt16 + NTOK;                              // (B*T,C) bf16
  __hip_bfloat16* Wcat = xb + NTOK;                                // (1536,768) bf16
  __hip_bfloat16* Wpb  = Wcat + (size_t)CX * C_;                   // (768,768) bf16
  int* ctr = (int*)(Wpb + (size_t)C_ * C_);                        // attn work queue
  __hip_bfloat16* yb   = xb;  // alias: xb dead after gemm1

  const int M = B_ * T_;

  cast_all<<<2048, 256, 0, stream>>>(x, W_la, W_v, W_proj, xb, Wcat, Wpb);

  gemm_bf16<64, true><<<dim3(M / 64, CX / 128), 256, 0, stream>>>(xb, Wcat, uxv, M, CX, C_);

  scan_seg<<<dim3(B_ * NH * NSEG / 4), 256, 0, stream>>>(uxv, la_coef, segend);
  scan_b<<<dim3((B_ * NH * HS + 255) / 256), 256, 0, stream>>>(la_coef, segend, carryin);
  scanc_vbuild<<<dim3(B_ * NH * NSEG / 4 + 32 * B_ * NH), 256, 0, stream>>>(
      la_coef, kernel_bet, carryin, uxv, v_coef, value_bet, kb16, vt16, ctr);

  attn13<<<dim3(512), 256, 0, stream>>>(kb16, vt16, kernel_bet, yb, ctr);

  gemm_bf16<64, false><<<dim3(M / 64, C_ / 128), 256, 0, stream>>>(yb, Wpb, out, M, C_, C_);
}

// Round 21
// 97.195 us; speedup vs baseline: 1.0669x; 1.0596x over previous
//
#include <hip/hip_runtime.h>
#include <hip/hip_bf16.h>
#include <math.h>

#define B_   2
#define T_   2048
#define C_   768
#define NH   12
#define HS   64
#define NSEG 64
#define SEGLEN 32
#define CX   1536   // uxv row stride (u | xv)

typedef __attribute__((ext_vector_type(8))) short short8;
typedef __attribute__((ext_vector_type(4))) short short4v;
typedef __attribute__((ext_vector_type(4))) float f32x4;
typedef __attribute__((ext_vector_type(16))) float f32x16;
typedef __attribute__((ext_vector_type(2))) unsigned int uint2v;
typedef __attribute__((ext_vector_type(4))) unsigned int uint4v;

static __device__ inline unsigned short f2b(float f) {
  __hip_bfloat16 h = __float2bfloat16(f);
  unsigned short u;
  __builtin_memcpy(&u, &h, 2);
  return u;
}
static __device__ inline float b2f(unsigned short u) {
  unsigned int x = ((unsigned int)u) << 16;
  float f;
  __builtin_memcpy(&f, &x, 4);
  return f;
}
static __device__ inline unsigned cvtpk(float a, float b) {
  unsigned r;
  asm("v_cvt_pk_bf16_f32 %0, %1, %2" : "=v"(r) : "v"(a), "v"(b));
  return r;
}

#define GLOAD_LDS16(gp, lp)                                                        \
  __builtin_amdgcn_global_load_lds((const __attribute__((address_space(1))) void*)(gp), \
                                   (__attribute__((address_space(3))) void*)(lp), 16, 0, 0)

// ---------------- f32 -> bf16 casts (weights only: W_la|W_v -> Wcat, W_proj) --------
__global__ __launch_bounds__(256) void cast_w(const float* __restrict__ wla,
                                              const float* __restrict__ wv,
                                              const float* __restrict__ wp,
                                              __hip_bfloat16* __restrict__ wcat,
                                              __hip_bfloat16* __restrict__ wpb) {
  const int NW4 = (C_ * C_) / 4;          // 147456
  const int TOT = 3 * NW4;
  int i = blockIdx.x * 256 + threadIdx.x;
  int st = gridDim.x * 256;
  for (; i < TOT; i += st) {
    const float* s;
    unsigned short* d;
    if (i < NW4) { s = wla + (size_t)i * 4; d = (unsigned short*)wcat + (size_t)i * 4; }
    else if (i < 2 * NW4) { int j = i - NW4; s = wv + (size_t)j * 4; d = (unsigned short*)wcat + (size_t)(C_ * C_) + (size_t)j * 4; }
    else { int j = i - 2 * NW4; s = wp + (size_t)j * 4; d = (unsigned short*)wpb + (size_t)j * 4; }
    float4 v = *(const float4*)s;
    short4v o;
    o.x = (short)f2b(v.x); o.y = (short)f2b(v.y); o.z = (short)f2b(v.z); o.w = (short)f2b(v.w);
    *(short4v*)d = o;
  }
}

// ---------------- bf16 MFMA GEMM with f32 A input (fused cast), BM=64 ---------------
// A is f32 (B*T, K); reg-staged + cvt_pk. Swizzle convention: LDS byte p of row r
// holds global byte p ^ ((r&7)<<4). Achieved by SWIZZLED SOURCE col (8*(slot^row8))
// + LINEAR dest (slot*16)  [rule #21: one permutation on write, same on read].
template <bool OB16>
__global__ __launch_bounds__(256) void gemm_xf32(const float* __restrict__ A,
                                                 const __hip_bfloat16* __restrict__ Bw,
                                                 void* __restrict__ Cv,
                                                 int M, int N, int K) {
  constexpr int BM = 64;
  __shared__ __hip_bfloat16 As[BM * 64];
  __shared__ __hip_bfloat16 Bs[128 * 64];
  const int tid = threadIdx.x;
  const int w = tid >> 6, lane = tid & 63;
  const int bm = blockIdx.x * BM, bn = blockIdx.y * 128;
  const int q16 = lane & 15, lg = lane >> 4;

  f32x4 acc[4][2];
#pragma unroll
  for (int i = 0; i < 4; ++i)
#pragma unroll
    for (int j = 0; j < 2; ++j) acc[i][j] = (f32x4){0.f, 0.f, 0.f, 0.f};

  const int srow = (lane >> 3);
  const int soff0 = (lane & 7) * 16;
  const int sw = (lane & 7) << 4;

  // A staging geometry: wave w handles chunks {2w, 2w+1}; lane: row8, slot
  const int row8 = lane >> 3, slot = lane & 7;
  const int colf = 8 * (slot ^ row8);        // swizzled f32 source col (8 elems)
  const int wb = row8 * 128 + slot * 16;     // LINEAR dest byte within chunk

  for (int k0 = 0; k0 < K; k0 += 64) {
    // issue A f32 loads to regs before the barrier
    float4 a0[2], a1[2];
#pragma unroll
    for (int n = 0; n < 2; ++n) {
      int ci = w * 2 + n;
      const float* ap = A + (size_t)(bm + ci * 8 + row8) * K + k0 + colf;
      a0[n] = *(const float4*)ap;
      a1[n] = *(const float4*)(ap + 4);
    }
    __syncthreads();
    // B staging via global_load_lds (16 chunks over 4 waves)
#pragma unroll
    for (int c = 0; c < 4; ++c) {
      int ci = w * 4 + c;
      int row = ci * 8 + srow;
      int soff = soff0 ^ ((row & 7) << 4);
      GLOAD_LDS16((const char*)(Bw + (size_t)(bn + row) * K + k0) + soff, Bs + ci * 512);
    }
    // A convert + linear ds_write (data already source-swizzled)
#pragma unroll
    for (int n = 0; n < 2; ++n) {
      uint4v pk;
      pk.x = cvtpk(a0[n].x, a0[n].y); pk.y = cvtpk(a0[n].z, a0[n].w);
      pk.z = cvtpk(a1[n].x, a1[n].y); pk.w = cvtpk(a1[n].z, a1[n].w);
      *(uint4v*)((char*)As + (w * 2 + n) * 1024 + wb) = pk;
    }
    __syncthreads();
#pragma unroll
    for (int ks = 0; ks < 2; ++ks) {
      short8 af[4], bf[2];
      const int colb = ks * 64 + lg * 16;
#pragma unroll
      for (int i = 0; i < 4; ++i) {
        int ra = i * 16 + q16;
        af[i] = *(const short8*)((const char*)As + ra * 128 + (colb ^ sw));
      }
#pragma unroll
      for (int j = 0; j < 2; ++j) {
        int rb = w * 32 + j * 16 + q16;
        bf[j] = *(const short8*)((const char*)Bs + rb * 128 + (colb ^ sw));
      }
#pragma unroll
      for (int i = 0; i < 4; ++i)
#pragma unroll
        for (int j = 0; j < 2; ++j)
          acc[i][j] = __builtin_amdgcn_mfma_f32_16x16x32_bf16(af[i], bf[j], acc[i][j], 0, 0, 0);
    }
  }
#pragma unroll
  for (int i = 0; i < 4; ++i) {
#pragma unroll
    for (int r = 0; r < 4; ++r) {
      int m = bm + i * 16 + lg * 4 + r;
      int nb = bn + w * 32 + q16;
      if (OB16) {
        unsigned short* cp = (unsigned short*)Cv + (size_t)m * N + nb;
#pragma unroll
        for (int j = 0; j < 2; ++j) cp[j * 16] = f2b(acc[i][j][r]);
      } else {
        float* cp = (float*)Cv + (size_t)m * N + nb;
#pragma unroll
        for (int j = 0; j < 2; ++j) cp[j * 16] = acc[i][j][r];
      }
    }
  }
}

// ---------------- bf16 MFMA GEMM: C[m,n] = sum_k A[m,k] * Bw[n,k], BM=64 ------------
template <bool OB16>
__global__ __launch_bounds__(256) void gemm_bf16(const __hip_bfloat16* __restrict__ A,
                                                 const __hip_bfloat16* __restrict__ Bw,
                                                 void* __restrict__ Cv,
                                                 int M, int N, int K) {
  constexpr int BM = 64;
  __shared__ __hip_bfloat16 As[BM * 64];
  __shared__ __hip_bfloat16 Bs[128 * 64];
  const int tid = threadIdx.x;
  const int w = tid >> 6, lane = tid & 63;
  const int bm = blockIdx.x * BM, bn = blockIdx.y * 128;
  const int q16 = lane & 15, lg = lane >> 4;

  f32x4 acc[4][2];
#pragma unroll
  for (int i = 0; i < 4; ++i)
#pragma unroll
    for (int j = 0; j < 2; ++j) acc[i][j] = (f32x4){0.f, 0.f, 0.f, 0.f};

  const int srow = (lane >> 3);
  const int soff0 = (lane & 7) * 16;
  const int sw = (lane & 7) << 4;
  constexpr int ACH = BM / 8;            // 8 A chunks
  constexpr int CPW = (ACH + 16) / 4;    // 6 chunks per wave

  for (int k0 = 0; k0 < K; k0 += 64) {
    __syncthreads();
#pragma unroll
    for (int c = 0; c < CPW; ++c) {
      int gc = w * CPW + c;
      int isB = gc >= ACH;
      int ci = isB ? gc - ACH : gc;
      int row = ci * 8 + srow;
      int soff = soff0 ^ ((row & 7) << 4);
      const __hip_bfloat16* gp =
          (isB ? Bw + (size_t)(bn + row) * K : A + (size_t)(bm + row) * K) + k0 + (soff >> 1);
      __hip_bfloat16* lp = (isB ? Bs : As) + ci * 512;
      GLOAD_LDS16(gp, lp);
    }
    __syncthreads();
#pragma unroll
    for (int ks = 0; ks < 2; ++ks) {
      short8 af[4], bf[2];
      const int colb = ks * 64 + lg * 16;
#pragma unroll
      for (int i = 0; i < 4; ++i) {
        int ra = i * 16 + q16;
        af[i] = *(const short8*)((const char*)As + ra * 128 + (colb ^ sw));
      }
#pragma unroll
      for (int j = 0; j < 2; ++j) {
        int rb = w * 32 + j * 16 + q16;
        bf[j] = *(const short8*)((const char*)Bs + rb * 128 + (colb ^ sw));
      }
#pragma unroll
      for (int i = 0; i < 4; ++i)
#pragma unroll
        for (int j = 0; j < 2; ++j)
          acc[i][j] = __builtin_amdgcn_mfma_f32_16x16x32_bf16(af[i], bf[j], acc[i][j], 0, 0, 0);
    }
  }
#pragma unroll
  for (int i = 0; i < 4; ++i) {
#pragma unroll
    for (int r = 0; r < 4; ++r) {
      int m = bm + i * 16 + lg * 4 + r;
      int nb = bn + w * 32 + q16;
      if (OB16) {
        unsigned short* cp = (unsigned short*)Cv + (size_t)m * N + nb;
#pragma unroll
        for (int j = 0; j < 2; ++j) cp[j * 16] = f2b(acc[i][j][r]);
      } else {
        float* cp = (float*)Cv + (size_t)m * N + nb;
#pragma unroll
        for (int j = 0; j < 2; ++j) cp[j * 16] = acc[i][j][r];
      }
    }
  }
}

// ---------------- Scan pass A: segment end-carries (bf16 u, prefetched loads) -------
__global__ __launch_bounds__(256) void scan_seg(const unsigned short* __restrict__ uxv,
                                                const float* __restrict__ la_coef,
                                                float* __restrict__ segend) {
  int cid = blockIdx.x * 4 + (threadIdx.x >> 6);  // bh*NSEG + seg
  int d   = threadIdx.x & 63;
  int seg = cid & (NSEG - 1);
  int bh  = cid >> 6;
  int h   = bh % NH;
  int b   = bh / NH;
  float c  = la_coef[h];
  float oc = 1.f - c;
  int t0 = seg * SEGLEN;
  const unsigned short* up = uxv + ((size_t)b * T_ + t0) * CX + h * HS + d;
  float uv[SEGLEN];
#pragma unroll
  for (int i = 0; i < SEGLEN; ++i) uv[i] = b2f(up[(size_t)i * CX]);
  float y = 0.f;
#pragma unroll
  for (int i = 0; i < SEGLEN; ++i) y = fmaf(c, y, oc * uv[i]);
  segend[(size_t)cid * HS + d] = y;
}

// ---------------- Scan pass B: combine segment carries (prefetched) -----------------
__global__ __launch_bounds__(256) void scan_b(const float* __restrict__ la_coef,
                                              const float* __restrict__ segend,
                                              float* __restrict__ carryin) {
  int s = blockIdx.x * 256 + threadIdx.x;  // (b,h,d)
  if (s >= B_ * NH * HS) return;
  int d  = s & 63;
  int bh = s >> 6;
  int h  = bh % NH;
  float c = la_coef[h];
  float cl = c;
#pragma unroll
  for (int i = 0; i < 5; ++i) cl *= cl;  // c^32
  float sv[NSEG];
#pragma unroll
  for (int seg = 0; seg < NSEG; ++seg)
    sv[seg] = segend[(size_t)(bh * NSEG + seg) * HS + d];
  float h0 = 0.f;
#pragma unroll
  for (int seg = 0; seg < NSEG; ++seg) {
    carryin[(size_t)(bh * NSEG + seg) * HS + d] = h0;
    h0 = fmaf(cl, h0, sv[seg]);
  }
}

// ---------------- Fused: scan_c+normalize (blocks 0..383) | vbuild_t (384..1151) ----
__global__ __launch_bounds__(256) void scanc_vbuild(const float* __restrict__ la_coef,
                                                    const float* __restrict__ kernel_beta,
                                                    const float* __restrict__ carryin,
                                                    const unsigned short* __restrict__ uxv,
                                                    const float* __restrict__ v_coef,
                                                    const float* __restrict__ value_beta,
                                                    __hip_bfloat16* __restrict__ kb16,
                                                    __hip_bfloat16* __restrict__ vt) {
  __shared__ __hip_bfloat16 sm[64][73];
  const int NBC = B_ * NH * NSEG / 4;   // 384 scan_c blocks
  if ((int)blockIdx.x < NBC) {
    int cid = blockIdx.x * 4 + (threadIdx.x >> 6);
    int d   = threadIdx.x & 63;
    int seg = cid & (NSEG - 1);
    int bh  = cid >> 6;
    int h   = bh % NH;
    int b   = bh / NH;
    float c  = la_coef[h];
    float oc = 1.f - c;
    float bk = __expf(fminf(kernel_beta[h] * 10.f, 5.f));
    int t0 = seg * SEGLEN;
    const unsigned short* up = uxv + ((size_t)b * T_ + t0) * CX + h * HS + d;
    __hip_bfloat16* op = kb16 + ((size_t)bh * T_ + t0) * HS + d;
    float uv[SEGLEN];
#pragma unroll
    for (int i = 0; i < SEGLEN; ++i) uv[i] = b2f(up[(size_t)i * CX]);
    float y = carryin[(size_t)cid * HS + d];
    for (int i = 0; i < SEGLEN; ++i) {
      y = fmaf(c, y, oc * uv[i]);
      float ss = y * y;
#pragma unroll
      for (int off = 1; off < 64; off <<= 1) ss += __shfl_xor(ss, off, 64);
      float scale = bk / (sqrtf(ss) + 1e-6f);
      op[(size_t)i * HS] = __float2bfloat16(y * scale);
    }
  } else {
    int idx = blockIdx.x - NBC;
    int t0 = (idx & 31) * 64;
    int bh = idx >> 5;
    int h = bh % NH, b = bh / NH;
    int w = threadIdx.x >> 6, lane = threadIdx.x & 63;
    float vc = v_coef[h];
    float vb = __expf(fminf(value_beta[h] * 10.f, 5.f));
    for (int i = 0; i < 16; ++i) {
      int tl = w * 16 + i;
      int t = t0 + tl;
      const unsigned short* xp = uxv + ((size_t)b * T_ + t) * CX + 768 + h * HS + lane;
      float x0 = b2f(*xp);
      float x1 = (t + 1 < T_) ? b2f(xp[CX]) : 0.f;
      float vf = (1.f - vc) * x1 + vc * x0;
      float ss = vf * vf;
#pragma unroll
      for (int off = 1; off < 64; off <<= 1) ss += __shfl_xor(ss, off, 64);
      sm[tl][lane] = __float2bfloat16(vf * vb / (sqrtf(ss) + 1e-6f));
    }
    __syncthreads();
    int d = threadIdx.x >> 3;
    int c = threadIdx.x & 7;
    for (int i = 0; i < 2; ++i) {
      int dd = d + i * 32;
      short8 v;
#pragma unroll
      for (int k = 0; k < 8; ++k)
        v[k] = (short)((const unsigned short*)&sm[c * 8 + k][dd])[0];
      *(short8*)((unsigned short*)vt + ((size_t)bh * HS + dd) * T_ + t0 + c * 8) = v;
    }
  }
}

// ---------------- attention v11 (best measured: 41.8us): 32x32 MFMA, in-reg P -------
__global__ __launch_bounds__(256, 2) void attn11(const __hip_bfloat16* __restrict__ Kg,
                                                 const __hip_bfloat16* __restrict__ Vtg,
                                                 const float* __restrict__ kernel_beta,
                                                 __hip_bfloat16* __restrict__ Y) {
  __shared__ __align__(16) char lds[41984];  // 2 x 20KB combine bufs + 1KB lsum
  const int bh = blockIdx.x;
  const int b = bh / NH, h = bh % NH;
  const int w = threadIdx.x >> 6, lane = threadIdx.x & 63;
  const int l31 = lane & 31, lg2 = lane >> 5;
  const int it = 31 - blockIdx.y;            // heavy-first
  const int qb0 = 1 + it * 64;
  const int NT32 = 2 * it + 2;               // 32-key tiles covering j <= qb0+62
  const int NTU = NT32 - 2;                  // kt < NTU: fully unmasked
  float bk = __expf(fminf(kernel_beta[h] * 10.f, 5.f));
  const float L2E = 1.4426950408889634f;
  const float m0l = bk * bk * L2E;
  const unsigned short* Kh = (const unsigned short*)Kg + (size_t)bh * T_ * HS;
  const unsigned short* Vh = (const unsigned short*)Vtg + (size_t)bh * HS * T_;
  unsigned short* Yh = (unsigned short*)Y + (size_t)b * T_ * C_ + h * HS;

  if (it == 0 && w == 0) Yh[lane] = 0;  // t=0 row zero

  short8 qf[2][4];
#pragma unroll
  for (int qs = 0; qs < 2; ++qs) {
    int tqc = qb0 + qs * 32 + l31;
    if (tqc > T_ - 1) tqc = T_ - 1;
#pragma unroll
    for (int s = 0; s < 4; ++s)
      qf[qs][s] = *(const short8*)(Kh + (size_t)tqc * HS + s * 16 + lg2 * 8);
  }

  f32x16 zero16 = {0.f};
  f32x16 accO[2][2];
#pragma unroll
  for (int qs = 0; qs < 2; ++qs)
#pragma unroll
    for (int ds = 0; ds < 2; ++ds) accO[qs][ds] = zero16;
  float lsum[2] = {0.f, 0.f};

#define LOADT(KF, VF, j0)                                                             \
  {                                                                                   \
    _Pragma("unroll")                                                                 \
    for (int s = 0; s < 4; ++s)                                                       \
      KF[s] = *(const short8*)(Kh + (size_t)((j0) + l31) * HS + s * 16 + lg2 * 8);    \
    _Pragma("unroll")                                                                 \
    for (int ds = 0; ds < 2; ++ds)                                                    \
      _Pragma("unroll")                                                               \
      for (int s2 = 0; s2 < 2; ++s2)                                                  \
        VF[ds][s2] = *(const short8*)(Vh + (size_t)(ds * 32 + l31) * T_ + (j0) +      \
                                      s2 * 16 + lg2 * 8);                             \
  }

#define PV_STEP(VF, qs)                                                               \
  {                                                                                   \
    __builtin_amdgcn_s_setprio(1);                                                    \
    _Pragma("unroll")                                                                 \
    for (int ds = 0; ds < 2; ++ds) {                                                  \
      accO[qs][ds] = __builtin_amdgcn_mfma_f32_32x32x16_bf16(VF[ds][0], PB0,          \
                                                             accO[qs][ds], 0, 0, 0);  \
      accO[qs][ds] = __builtin_amdgcn_mfma_f32_32x32x16_bf16(VF[ds][1], PB1,          \
                                                             accO[qs][ds], 0, 0, 0);  \
    }                                                                                 \
    __builtin_amdgcn_s_setprio(0);                                                    \
  }

#define PACK_P()                                                                      \
  uint2v g00 = __builtin_amdgcn_permlane32_swap(cvtpk(p[0], p[1]),                    \
                                                cvtpk(p[4], p[5]), false, false);     \
  uint2v g01 = __builtin_amdgcn_permlane32_swap(cvtpk(p[2], p[3]),                    \
                                                cvtpk(p[6], p[7]), false, false);     \
  uint2v g10 = __builtin_amdgcn_permlane32_swap(cvtpk(p[8], p[9]),                    \
                                                cvtpk(p[12], p[13]), false, false);   \
  uint2v g11 = __builtin_amdgcn_permlane32_swap(cvtpk(p[10], p[11]),                  \
                                                cvtpk(p[14], p[15]), false, false);   \
  uint4v pb0v, pb1v;                                                                  \
  pb0v.x = g00.x; pb0v.y = g01.x; pb0v.z = g00.y; pb0v.w = g01.y;                     \
  pb1v.x = g10.x; pb1v.y = g11.x; pb1v.z = g10.y; pb1v.w = g11.y;                     \
  short8 PB0 = __builtin_bit_cast(short8, pb0v);                                      \
  short8 PB1 = __builtin_bit_cast(short8, pb1v);

#define COMPUTE_U(KF, VF)                                                             \
  {                                                                                   \
    _Pragma("unroll")                                                                 \
    for (int qs = 0; qs < 2; ++qs) {                                                  \
      f32x16 S = zero16;                                                              \
      __builtin_amdgcn_s_setprio(1);                                                  \
      _Pragma("unroll")                                                               \
      for (int s = 0; s < 4; ++s)                                                     \
        S = __builtin_amdgcn_mfma_f32_32x32x16_bf16(KF[s], qf[qs][s], S, 0, 0, 0);    \
      __builtin_amdgcn_s_setprio(0);                                                  \
      float p[16];                                                                    \
      _Pragma("unroll")                                                               \
      for (int r = 0; r < 16; ++r) {                                                  \
        p[r] = exp2f(fmaf(S[r], L2E, -m0l));                                          \
        lsum[qs] += p[r];                                                             \
      }                                                                               \
      PACK_P();                                                                       \
      PV_STEP(VF, qs);                                                                \
    }                                                                                 \
  }

#define COMPUTE_M(KF, VF, ktv)                                                        \
  {                                                                                   \
    const int jb = (ktv)*32 + 4 * lg2;                                                \
    _Pragma("unroll")                                                                 \
    for (int qs = 0; qs < 2; ++qs) {                                                  \
      const int tqq = qb0 + qs * 32 + l31;                                            \
      f32x16 S = zero16;                                                              \
      _Pragma("unroll")                                                               \
      for (int s = 0; s < 4; ++s)                                                     \
        S = __builtin_amdgcn_mfma_f32_32x32x16_bf16(KF[s], qf[qs][s], S, 0, 0, 0);    \
      float p[16];                                                                    \
      _Pragma("unroll")                                                               \
      for (int r = 0; r < 16; ++r) {                                                  \
        int jg = jb + (r & 3) + 8 * (r >> 2);                                         \
        p[r] = (jg < tqq) ? exp2f(fmaf(S[r], L2E, -m0l)) : 0.f;                       \
        lsum[qs] += p[r];                                                             \
      }                                                                               \
      PACK_P();                                                                       \
      PV_STEP(VF, qs);                                                                \
    }                                                                                 \
  }

  short8 kfA[4], vfA[2][2], kfB[4], vfB[2][2];
  int kt = w;
  if (kt < NTU) {
    LOADT(kfA, vfA, kt * 32);
    while (true) {
      if (kt + 4 < NTU) LOADT(kfB, vfB, (kt + 4) * 32);
      COMPUTE_U(kfA, vfA);
      kt += 4;
      if (kt >= NTU) break;
      if (kt + 4 < NTU) LOADT(kfA, vfA, (kt + 4) * 32);
      COMPUTE_U(kfB, vfB);
      kt += 4;
      if (kt >= NTU) break;
    }
  }
  for (; kt < NT32; kt += 4) {
    LOADT(kfA, vfA, kt * 32);
    COMPUTE_M(kfA, vfA, kt);
  }

#pragma unroll
  for (int qs = 0; qs < 2; ++qs) lsum[qs] += __shfl_xor(lsum[qs], 32, 64);

  // ---- tree combine over waves; rows at 80B stride (8-way max bank aliasing) ------
  float* LR = (float*)(lds + 40960);  // [w][qs][l31]
  __syncthreads();
  if (w >= 2) {
    float* PB = (float*)(lds + (size_t)(w - 2) * 20480);
#pragma unroll
    for (int qs = 0; qs < 2; ++qs)
#pragma unroll
      for (int ds = 0; ds < 2; ++ds) {
        float* rb = PB + ((qs * 2 + ds) * 64 + lane) * 20;
#pragma unroll
        for (int c = 0; c < 4; ++c)
          *(f32x4*)(rb + c * 4) = (f32x4){accO[qs][ds][c * 4 + 0], accO[qs][ds][c * 4 + 1],
                                          accO[qs][ds][c * 4 + 2], accO[qs][ds][c * 4 + 3]};
      }
  }
#pragma unroll
  for (int qs = 0; qs < 2; ++qs) LR[(w * 2 + qs) * 32 + l31] = lsum[qs];
  __syncthreads();
  if (w < 2) {
    float* PB = (float*)(lds + (size_t)w * 20480);
#pragma unroll
    for (int qs = 0; qs < 2; ++qs)
#pragma unroll
      for (int ds = 0; ds < 2; ++ds) {
        float* rb = PB + ((qs * 2 + ds) * 64 + lane) * 20;
#pragma unroll
        for (int c = 0; c < 4; ++c) {
          f32x4 o = *(f32x4*)(rb + c * 4);
          accO[qs][ds][c * 4 + 0] += o[0]; accO[qs][ds][c * 4 + 1] += o[1];
          accO[qs][ds][c * 4 + 2] += o[2]; accO[qs][ds][c * 4 + 3] += o[3];
        }
      }
    if (w == 1) {
#pragma unroll
      for (int qs = 0; qs < 2; ++qs)
#pragma unroll
        for (int ds = 0; ds < 2; ++ds) {
          float* rb = PB + ((qs * 2 + ds) * 64 + lane) * 20;
#pragma unroll
          for (int c = 0; c < 4; ++c)
            *(f32x4*)(rb + c * 4) = (f32x4){accO[qs][ds][c * 4 + 0], accO[qs][ds][c * 4 + 1],
                                            accO[qs][ds][c * 4 + 2], accO[qs][ds][c * 4 + 3]};
        }
    }
  }
  __syncthreads();
  if (w == 0) {
    float* PB1 = (float*)(lds + 20480);
#pragma unroll
    for (int qs = 0; qs < 2; ++qs) {
#pragma unroll
      for (int ds = 0; ds < 2; ++ds) {
        float* rb = PB1 + ((qs * 2 + ds) * 64 + lane) * 20;
#pragma unroll
        for (int c = 0; c < 4; ++c) {
          f32x4 o = *(f32x4*)(rb + c * 4);
          accO[qs][ds][c * 4 + 0] += o[0]; accO[qs][ds][c * 4 + 1] += o[1];
          accO[qs][ds][c * 4 + 2] += o[2]; accO[qs][ds][c * 4 + 3] += o[3];
        }
      }
      float tot = LR[(0 * 2 + qs) * 32 + l31] + LR[(1 * 2 + qs) * 32 + l31] +
                  LR[(2 * 2 + qs) * 32 + l31] + LR[(3 * 2 + qs) * 32 + l31];
      float inv = 1.f / tot;
      int tq = qb0 + qs * 32 + l31;
      if (tq < T_) {
        unsigned short* yp = Yh + (size_t)tq * C_;
#pragma unroll
        for (int ds = 0; ds < 2; ++ds)
#pragma unroll
          for (int r = 0; r < 16; r += 2) {
            int d = ds * 32 + (r & 3) + 8 * (r >> 2) + 4 * lg2;
            unsigned u = cvtpk(accO[qs][ds][r] * inv, accO[qs][ds][r + 1] * inv);
            *(unsigned*)(yp + d) = u;
          }
      }
    }
  }
#undef LOADT
#undef COMPUTE_U
#undef COMPUTE_M
#undef PACK_P
#undef PV_STEP
}

extern "C" void kernel_launch(void* const* d_in, const int* in_sizes, int n_in,
                              void* d_out, int out_size, void* d_ws, size_t ws_size,
                              hipStream_t stream) {
  const float* x          = (const float*)d_in[0];
  const float* W_la       = (const float*)d_in[1];
  const float* la_coef    = (const float*)d_in[2];
  const float* W_v        = (const float*)d_in[3];
  const float* v_coef     = (const float*)d_in[4];
  const float* kernel_bet = (const float*)d_in[5];
  const float* value_bet  = (const float*)d_in[6];
  const float* W_proj     = (const float*)d_in[7];
  float* out = (float*)d_out;

  char* ws = (char*)d_ws;
  const size_t NTOK = (size_t)B_ * T_ * C_;            // 3,145,728
  const size_t NSEGTOT = (size_t)B_ * NH * NSEG * HS;  // 98,304
  unsigned short* uxv = (unsigned short*)ws;                       // (B*T, CX) bf16
  float* segend  = (float*)(ws + (size_t)B_ * T_ * CX * 2);
  float* carryin = segend + NSEGTOT;
  __hip_bfloat16* kb16 = (__hip_bfloat16*)(carryin + NSEGTOT);     // (B,NH,T,HS)
  __hip_bfloat16* vt16 = kb16 + NTOK;                              // (B,NH,HS,T)
  __hip_bfloat16* yb   = vt16 + NTOK;                              // (B*T,C) bf16 attn out
  __hip_bfloat16* Wcat = yb + NTOK;                                // (1536,768) bf16
  __hip_bfloat16* Wpb  = Wcat + (size_t)CX * C_;                   // (768,768) bf16

  const int M = B_ * T_;

  cast_w<<<1024, 256, 0, stream>>>(W_la, W_v, W_proj, Wcat, Wpb);

  // uxv (bf16) = x(f32) @ [W_la; W_v]^T  — fused cast in A staging
  gemm_xf32<true><<<dim3(M / 64, CX / 128), 256, 0, stream>>>(x, Wcat, uxv, M, CX, C_);

  scan_seg<<<dim3(B_ * NH * NSEG / 4), 256, 0, stream>>>(uxv, la_coef, segend);
  scan_b<<<dim3((B_ * NH * HS + 255) / 256), 256, 0, stream>>>(la_coef, segend, carryin);
  scanc_vbuild<<<dim3(B_ * NH * NSEG / 4 + 32 * B_ * NH), 256, 0, stream>>>(
      la_coef, kernel_bet, carryin, uxv, v_coef, value_bet, kb16, vt16);

  attn11<<<dim3(B_ * NH, 32), 256, 0, stream>>>(kb16, vt16, kernel_bet, yb);

  gemm_bf16<false><<<dim3(M / 64, C_ / 128), 256, 0, stream>>>(yb, Wpb, out, M, C_, C_);
}